// Round 8
// baseline (124.478 us; speedup 1.0000x reference)
//
#include <hip/hip_runtime.h>

// Problem constants (fixed by the reference file).
#define GH 7
#define GW 7
#define HIMG 256
#define WIMG 256
#define CIMG 256
#define NBOXES 1000
#define NCELLS (NBOXES * GH * GW)   // 49000

// 2 cells per wave -> 8 independent 1KB loads in flight per wave.
#define CELLS_PER_BLOCK 8           // 4 waves * 2 cells
#define NBLOCKS (NCELLS / CELLS_PER_BLOCK)  // 6125 exactly

typedef float f32x4 __attribute__((ext_vector_type(4)));

// One wave handles TWO output cells; each lane does 4 channels via f32x4.
// NHWC => channel dim contiguous: each pixel read is 64 lanes x 16B = 1KB
// fully coalesced. Output stores are nontemporal (never re-read).
// Bijective XCD swizzle (m204): consecutive logical blocks (= cells of the
// same box, which share bilinear neighbor pixels) land on the SAME XCD's L2.
//
// NOTE (round 6 lesson): box normalization MUST be exact division by (w-1)
// to match the reference bit-for-bit. Boxes clipped to exactly 255 put in_y
// exactly on the `<= 255` validity boundary; reciprocal-multiply shifts it
// 1 ulp and flips the mask -> absmax ~3 failures.
__global__ __launch_bounds__(256) void roi_kernel(
    const float* __restrict__ meta,
    const float* __restrict__ img,
    const float* __restrict__ boxes,
    float* __restrict__ out)
{
    const int wave = threadIdx.x >> 6;
    const int lane = threadIdx.x & 63;

    // ---- bijective XCD swizzle: nwg=6125 = 8*765 + 5 ----
    const int q = NBLOCKS / 8;   // 765
    const int r = NBLOCKS % 8;   // 5
    const int bid = blockIdx.x;
    const int xcd = bid & 7;
    const int idx = bid >> 3;
    const int lb = (xcd < r) ? (xcd * (q + 1) + idx)
                             : (r * (q + 1) + (xcd - r) * q + idx);

    const int cell0 = lb * CELLS_PER_BLOCK + wave * 2;

    const float h = meta[0];
    const float w = meta[1];

    f32x4 g[2][4];
    float lxv[2], lyv[2];
    bool validv[2];

    #pragma unroll
    for (int c = 0; c < 2; ++c) {
        const int cell = cell0 + c;
        const int b  = cell / (GH * GW);
        const int gg = cell - b * (GH * GW);
        const int gy = gg / GW;
        const int gx = gg - gy * GW;

        // Exact divisions — replicate reference op-for-op (see NOTE above).
        const float bx1 = boxes[b * 4 + 0] / (w - 1.0f);
        const float by1 = boxes[b * 4 + 1] / (h - 1.0f);
        const float bx2 = boxes[b * 4 + 2] / (w - 1.0f);
        const float by2 = boxes[b * 4 + 3] / (h - 1.0f);

        const float ty = (float)gy / (float)(GH - 1);
        const float tx = (float)gx / (float)(GW - 1);

        const float in_y = (by1 + ty * (by2 - by1)) * (float)(HIMG - 1);
        const float in_x = (bx1 + tx * (bx2 - bx1)) * (float)(WIMG - 1);

        validv[c] = (in_y >= 0.0f) && (in_y <= (float)(HIMG - 1)) &&
                    (in_x >= 0.0f) && (in_x <= (float)(WIMG - 1));

        const float y0f = floorf(in_y);
        const float x0f = floorf(in_x);
        lyv[c] = in_y - y0f;
        lxv[c] = in_x - x0f;

        const int y0 = (int)fminf(fmaxf(y0f,        0.0f), (float)(HIMG - 1));
        const int y1 = (int)fminf(fmaxf(y0f + 1.0f, 0.0f), (float)(HIMG - 1));
        const int x0 = (int)fminf(fmaxf(x0f,        0.0f), (float)(WIMG - 1));
        const int x1 = (int)fminf(fmaxf(x0f + 1.0f, 0.0f), (float)(WIMG - 1));

        // Issue all 4 loads for this cell (8 in flight across the pair).
        g[c][0] = *((const f32x4*)(img + (size_t)(y0 * WIMG + x0) * CIMG) + lane);
        g[c][1] = *((const f32x4*)(img + (size_t)(y0 * WIMG + x1) * CIMG) + lane);
        g[c][2] = *((const f32x4*)(img + (size_t)(y1 * WIMG + x0) * CIMG) + lane);
        g[c][3] = *((const f32x4*)(img + (size_t)(y1 * WIMG + x1) * CIMG) + lane);
    }

    #pragma unroll
    for (int c = 0; c < 2; ++c) {
        const float lx = lxv[c], ly = lyv[c];
        const float omlx = 1.0f - lx, omly = 1.0f - ly;

        // Reference blend order: top = g00*(1-lx)+g01*lx; bot likewise;
        // out = top*(1-ly) + bot*ly.
        f32x4 o = (g[c][0] * omlx + g[c][1] * lx) * omly +
                  (g[c][2] * omlx + g[c][3] * lx) * ly;
        if (!validv[c]) o = (f32x4)0.0f;

        f32x4* op = (f32x4*)(out + (size_t)(cell0 + c) * CIMG) + lane;
        __builtin_nontemporal_store(o, op);
    }
}

extern "C" void kernel_launch(void* const* d_in, const int* in_sizes, int n_in,
                              void* d_out, int out_size, void* d_ws, size_t ws_size,
                              hipStream_t stream) {
    const float* meta  = (const float*)d_in[0];
    const float* img   = (const float*)d_in[1];
    const float* boxes = (const float*)d_in[2];
    float* out = (float*)d_out;

    dim3 grid(NBLOCKS);   // 6125
    dim3 block(256);
    roi_kernel<<<grid, block, 0, stream>>>(meta, img, boxes, out);
}